// Round 7
// baseline (56.536 us; speedup 1.0000x reference)
//
#include <hip/hip_runtime.h>
#include <math.h>

#define IMG 224
#define NPIX 50176
#define BATCH 64
#define EDIM 256

typedef _Float16 f16;
typedef __attribute__((ext_vector_type(8))) _Float16 f16x8;
typedef __attribute__((ext_vector_type(4))) _Float16 f16x4;
typedef __attribute__((ext_vector_type(4))) float f32x4;
typedef unsigned int u32;

// Stage A (fused gray): A = mean_c x[b,c,h,:] -> f16, direct from x (reg-staged,
//   T14 issue-early/write-late), B = B1[256][256] via global_load_lds.
//   Block tile 64(M) x 256(N), BK=64, 4 waves (2Mx2N), wave tile 32x128.
// Stage B: A=W2[448][448] (rows 2u=re,2u+1=im), B=B2t[b][128][448];
//   epilogue: log1p(|F|) + radial-band stats fused (atomics, no mag buffer).

#define GLD16(gp, lp)                                                          \
  __builtin_amdgcn_global_load_lds(                                            \
      (const __attribute__((address_space(1))) u32*)(gp),                      \
      (__attribute__((address_space(3))) u32*)(lp), 16, 0, 0)

// ---- gemmA: Y = gray(x) * B1^T, gray fused into A-staging -----------------
__global__ __launch_bounds__(256) void gemmA_kernel(const float* __restrict__ x,
                                                    const f16* __restrict__ B1,
                                                    f16* __restrict__ B2t) {
  __shared__ f16 As[2][64][64];     // 16 KB
  __shared__ f16 Bs[2][256][64];    // 64 KB
  int m0 = blockIdx.x * 64;
  int tid = threadIdx.x;
  int lane = tid & 63, wid = tid >> 6;
  int wr = wid >> 1, wc = wid & 1;

  // A reg-staging assignment: thread -> (row, 16-col segment)
  int arow = tid >> 2;             // 0..63
  int aseg = tid & 3;              // cols aseg*16 .. +15
  int am = m0 + arow;
  int ab = am / 224, ah = am - ab * 224;
  const float* px = x + (size_t)ab * 3 * NPIX + ah * IMG;
  int s0 = (aseg * 2) ^ (arow & 7);        // swizzled 16B slots (involution)
  int s1 = (aseg * 2 + 1) ^ (arow & 7);

  // B staging (global_load_lds) lane mapping
  int srow = lane >> 3;
  int sk8 = (lane & 7) ^ srow;

  f32x4 xl[3][4];

  f32x4 acc[2][8];
#pragma unroll
  for (int i = 0; i < 2; ++i)
#pragma unroll
    for (int j = 0; j < 8; ++j) acc[i][j] = (f32x4){0.f, 0.f, 0.f, 0.f};

  auto issueA = [&](int t) {
    int kb = t * 64 + aseg * 16;
    if (kb < 224) {
#pragma unroll
      for (int c = 0; c < 3; ++c)
#pragma unroll
        for (int q = 0; q < 4; ++q)
          xl[c][q] = *(const f32x4*)(px + c * NPIX + kb + q * 4);
    }
  };
  auto issueB = [&](int bufi, int t) {
    int k0 = t * 64;
#pragma unroll
    for (int ci = 0; ci < 8; ++ci) {
      int j = wid * 8 + ci;
      GLD16(B1 + (size_t)(j * 8 + srow) * 256 + k0 + sk8 * 8,
            &Bs[bufi][0][0] + j * 512);
    }
  };
  auto writeA = [&](int bufi, int t) {
    int kb = t * 64 + aseg * 16;
    f16x8 h0, h1;
    if (kb < 224) {
#pragma unroll
      for (int j = 0; j < 8; ++j) {
        int q = j >> 2, r = j & 3;
        h0[j] = (f16)((xl[0][q][r] + xl[1][q][r] + xl[2][q][r]) * (1.0f / 3.0f));
      }
#pragma unroll
      for (int j = 0; j < 8; ++j) {
        int q = 2 + (j >> 2), r = j & 3;
        h1[j] = (f16)((xl[0][q][r] + xl[1][q][r] + xl[2][q][r]) * (1.0f / 3.0f));
      }
    } else {
#pragma unroll
      for (int j = 0; j < 8; ++j) { h0[j] = (f16)0.f; h1[j] = (f16)0.f; }
    }
    *(f16x8*)&As[bufi][arow][s0 * 8] = h0;
    *(f16x8*)&As[bufi][arow][s1 * 8] = h1;
  };

  issueA(0);
  issueB(0, 0);
#pragma unroll 1
  for (int t = 0; t < 4; ++t) {
    int cur = t & 1;
    asm volatile("s_waitcnt vmcnt(0)" ::: "memory");   // x regs + B GLD16 (t) landed
    writeA(cur, t);
    asm volatile("s_waitcnt lgkmcnt(0)" ::: "memory");
    __builtin_amdgcn_s_barrier();                      // tile t fully staged
    if (t < 3) { issueA(t + 1); issueB(cur ^ 1, t + 1); }
#pragma unroll
    for (int kk = 0; kk < 2; ++kk) {
      f16x8 af[2], bfr[8];
#pragma unroll
      for (int mi = 0; mi < 2; ++mi) {
        int row = wr * 32 + mi * 16 + (lane & 15);
        int slot = (kk * 4 + (lane >> 4)) ^ (row & 7);
        af[mi] = *(const f16x8*)&As[cur][row][slot * 8];
      }
#pragma unroll
      for (int nj = 0; nj < 8; ++nj) {
        int row = wc * 128 + nj * 16 + (lane & 15);
        int slot = (kk * 4 + (lane >> 4)) ^ (row & 7);
        bfr[nj] = *(const f16x8*)&Bs[cur][row][slot * 8];
      }
#pragma unroll
      for (int mi = 0; mi < 2; ++mi)
#pragma unroll
        for (int nj = 0; nj < 8; ++nj)
          acc[mi][nj] = __builtin_amdgcn_mfma_f32_16x16x32_f16(
              af[mi], bfr[nj], acc[mi][nj], 0, 0, 0);
    }
    __builtin_amdgcn_s_barrier();
  }

  int mbase = m0 + wr * 32, nbase = wc * 128;
#pragma unroll
  for (int mi = 0; mi < 2; ++mi) {
#pragma unroll
    for (int nj = 0; nj < 8; ++nj) {
      int c = nbase + nj * 16 + (lane & 15);
      if (c >= 226) continue;
      int m = mbase + mi * 16 + ((lane >> 4) << 2);  // 4 consecutive rows, m%4==0
      int b = m / 224;
      int h = m - b * 224;                           // h%4==0, no image wrap
      int v = c, kb = h;
      if (c >= 113) { v = c - 113; kb = 224 + h; }
      size_t off = (size_t)(b * 128 + v) * 448 + kb;
      f32x4 y = acc[mi][nj];
      f16x4 hv;
#pragma unroll
      for (int r = 0; r < 4; ++r) hv[r] = (f16)y[r];
      *(f16x4*)&B2t[off] = hv;
    }
  }
}

// ---- gemmB core: double-buffered, counted vmcnt ---------------------------
template <int LDK, int NT>
__device__ __forceinline__ void gemm_core(const f16* __restrict__ A,
                                          const f16* __restrict__ B,
                                          int m0, int n0,
                                          f16 (*As)[64][64], f16 (*Bs)[128][64],
                                          f32x4 acc[2][4]) {
  int tid = threadIdx.x;
  int lane = tid & 63, wid = tid >> 6;
  int wr = wid >> 1, wc = wid & 1;
  int srow = lane >> 3;
  int sk8 = (lane & 7) ^ srow;

  auto stage = [&](int bufi, int t) {
    int k0 = t * 64;
#pragma unroll
    for (int ci = 0; ci < 6; ++ci) {
      int c = wid * 6 + ci;
      if (c < 8) {
        GLD16(A + (size_t)(m0 + c * 8 + srow) * LDK + k0 + sk8 * 8,
              &As[bufi][0][0] + c * 512);
      } else {
        int j = c - 8;
        GLD16(B + (size_t)(n0 + j * 8 + srow) * LDK + k0 + sk8 * 8,
              &Bs[bufi][0][0] + j * 512);
      }
    }
  };

  stage(0, 0);
#pragma unroll 1
  for (int t = 0; t < NT; ++t) {
    int cur = t & 1;
    if (t + 1 < NT) {
      stage(cur ^ 1, t + 1);
      asm volatile("s_waitcnt vmcnt(6)" ::: "memory");   // t done, t+1 in flight
    } else {
      asm volatile("s_waitcnt vmcnt(0)" ::: "memory");
    }
    __builtin_amdgcn_s_barrier();
#pragma unroll
    for (int kk = 0; kk < 2; ++kk) {
      f16x8 af[2], bfr[4];
#pragma unroll
      for (int mi = 0; mi < 2; ++mi) {
        int row = wr * 32 + mi * 16 + (lane & 15);
        int slot = (kk * 4 + (lane >> 4)) ^ (row & 7);
        af[mi] = *(const f16x8*)&As[cur][row][slot * 8];
      }
#pragma unroll
      for (int nj = 0; nj < 4; ++nj) {
        int row = wc * 64 + nj * 16 + (lane & 15);
        int slot = (kk * 4 + (lane >> 4)) ^ (row & 7);
        bfr[nj] = *(const f16x8*)&Bs[cur][row][slot * 8];
      }
#pragma unroll
      for (int mi = 0; mi < 2; ++mi)
#pragma unroll
        for (int nj = 0; nj < 4; ++nj)
          acc[mi][nj] = __builtin_amdgcn_mfma_f32_16x16x32_f16(
              af[mi], bfr[nj], acc[mi][nj], 0, 0, 0);
    }
    __builtin_amdgcn_s_barrier();
  }
}

// ---- stage B: F = W2 * B2t[b]^T; fused log1p(|F|) + band stats ------------
// stats layout: [0]=gsum [1]=gsumsq [2+k]=s1 [10+k]=s2 [18+k]=max [26+k]=cnt
__global__ __launch_bounds__(256) void gemmB_kernel(const f16* __restrict__ W2h,
                                                    const f16* __restrict__ B2t,
                                                    float* __restrict__ stats) {
  __shared__ f16 As[2][64][64];
  __shared__ f16 Bs[2][128][64];
  int b = blockIdx.x;                 // image
  int m0 = blockIdx.y * 64;           // W2 row block
  f32x4 acc[2][4];
#pragma unroll
  for (int i = 0; i < 2; ++i)
#pragma unroll
    for (int j = 0; j < 4; ++j) acc[i][j] = (f32x4){0.f, 0.f, 0.f, 0.f};

  gemm_core<448, 7>(W2h, B2t + (size_t)b * 128 * 448, m0, 0, As, Bs, acc);

  int tid = threadIdx.x;
  int lane = tid & 63, wid = tid >> 6;
  int wr = wid >> 1, wc = wid & 1;
  int rbase = m0 + wr * 32;
  const float step = (float)(158.39191898578665 / 8.0);

  float gsum = 0.f, gsq = 0.f;
  float s1[8] = {0}, s2[8] = {0}, cnt[8] = {0};
  float mx[8] = {0, 0, 0, 0, 0, 0, 0, 0};   // mag >= 0 always

#pragma unroll
  for (int mi = 0; mi < 2; ++mi) {
#pragma unroll
    for (int nj = 0; nj < 4; ++nj) {
      int n = wc * 64 + nj * 16 + (lane & 15);   // v, 0..127
      if (n >= 113) continue;
      float wgt = (n >= 1 && n <= 111) ? 2.f : 1.f;   // Hermitian mirror weight
      float dx2 = (float)(n * n);
      int rr = rbase + mi * 16 + ((lane >> 4) << 2);
      f32x4 f = acc[mi][nj];
#pragma unroll
      for (int p = 0; p < 2; ++p) {
        int u = (rr >> 1) + p;
        float re = f[2 * p], im = f[2 * p + 1];
        float mv = log1pf(sqrtf(re * re + im * im));
        int a = (u <= 111) ? u : 224 - u;
        float r = sqrtf((float)(a * a) + dx2);
        int bd = 255;
#pragma unroll
        for (int k = 0; k < 8; k++) {
          float lo = step * (float)k;
          float hi = step * (float)(k + 1);
          if (r >= lo && r < hi) bd = k;
        }
        float wm = wgt * mv;
        gsum += wm;
        gsq += wm * mv;
#pragma unroll
        for (int k = 0; k < 8; k++) {
          bool m = (bd == k);
          s1[k] += m ? wm : 0.f;
          s2[k] += m ? wm * mv : 0.f;
          cnt[k] += m ? wgt : 0.f;
          mx[k] = m ? fmaxf(mx[k], mv) : mx[k];
        }
      }
    }
  }

  float vals[34];
  vals[0] = gsum; vals[1] = gsq;
#pragma unroll
  for (int k = 0; k < 8; k++) {
    vals[2 + k] = s1[k]; vals[10 + k] = s2[k]; vals[18 + k] = mx[k]; vals[26 + k] = cnt[k];
  }
#pragma unroll
  for (int i = 0; i < 34; i++) {
    float v = vals[i];
    const bool isMax = (i >= 18 && i < 26);
#pragma unroll
    for (int off = 32; off > 0; off >>= 1) {
      float o = __shfl_down(v, off);
      v = isMax ? fmaxf(v, o) : (v + o);
    }
    vals[i] = v;
  }
  float* red = (float*)&As[0][0][0];   // reuse LDS (all reads done)
  if ((tid & 63) == 0) {
#pragma unroll
    for (int i = 0; i < 34; i++) red[wid * 34 + i] = vals[i];
  }
  __syncthreads();
  if (tid < 34) {
    bool isMax = (tid >= 18 && tid < 26);
    float v = red[tid];
#pragma unroll
    for (int ww = 1; ww < 4; ww++) {
      float o = red[ww * 34 + tid];
      v = isMax ? fmaxf(v, o) : (v + o);
    }
    if (isMax)
      atomicMax((u32*)&stats[b * 34 + tid], __float_as_uint(v));  // v >= 0
    else
      atomicAdd(&stats[b * 34 + tid], v);
  }
}

// ---- prep: tables only (B1 | W2 | B2t pad zero | stats zero) --------------
// blocks [0,256) b1; [256,1040) w2; [1040,1880) B2t pad; [1880,1889) stats
__global__ __launch_bounds__(256) void prep_kernel(f16* __restrict__ B1,
                                                   f16* __restrict__ W2h,
                                                   f16* __restrict__ B2t,
                                                   float* __restrict__ stats) {
  int blk = blockIdx.x;
  int tid = threadIdx.x;
  if (blk < 256) {
    int n = blk, k = tid;
    float val = 0.f;
    if (k < 224 && n < 226) {
      int v = (n < 113) ? n : n - 113;
      int m = (k * v) % 224;
      float mf = (float)m / 112.0f;
      val = (n < 113) ? cospif(mf) : -sinpif(mf);
    }
    B1[n * 256 + k] = (f16)val;
  } else if (blk < 1040) {
    int i = (blk - 256) * 256 + tid;       // 0..200703
    int row = i / 448;
    int k = i - row * 448;
    int u = row >> 1;
    bool imrow = row & 1;
    bool kim = k >= 224;
    int kk = kim ? k - 224 : k;
    int m = (u * kk) % 224;
    float mf = (float)m / 112.0f;
    float c = cospif(mf), s = sinpif(mf);
    // F_re = cos*Yr + sin*Yi ; F_im = -sin*Yr + cos*Yi
    float val = imrow ? (kim ? c : -s) : (kim ? s : c);
    W2h[i] = (f16)val;
  } else if (blk < 1880) {
    int w = (blk - 1040) * 256 + tid;      // 0..215039 u32 words
    int img = w / 3360;                    // 15 rows * 448 f16 / 2 per image
    int off = w - img * 3360;
    ((u32*)B2t)[(size_t)(img * 128 + 113) * 224 + off] = 0;
  } else {
    int i = (blk - 1880) * 256 + tid;
    if (i < BATCH * 34) stats[i] = 0.f;
  }
}

// ---- MLP ------------------------------------------------------------------
__global__ __launch_bounds__(256) void mlp_kernel(const float* __restrict__ stats,
                                                  const float* __restrict__ W1,
                                                  const float* __restrict__ b1,
                                                  const float* __restrict__ gamma,
                                                  const float* __restrict__ beta,
                                                  const float* __restrict__ W2m,
                                                  const float* __restrict__ b2,
                                                  float* __restrict__ out) {
  int bk = blockIdx.x;
  int b = bk >> 3, k = bk & 7;
  int e = threadIdx.x;

  __shared__ float st[34];
  if (e < 34) st[e] = stats[b * 34 + e];
  __syncthreads();

  const float N = (float)NPIX;
  float mu = st[0] / N;
  float varg = fmaxf(st[1] - N * mu * mu, 0.0f) / (N - 1.0f);
  float sd = sqrtf(varg) + 1e-6f;

  float s1r = st[2 + k], s2r = st[10 + k], mxr = st[18 + k], cntk = st[26 + k];
  float ms = cntk + 1e-6f;
  float s1n = (s1r - mu * cntk) / sd;
  float s2n = (s2r - 2.0f * mu * s1r + mu * mu * cntk) / (sd * sd);
  float mean_k = s1n / ms;
  float var_num = s2n - 2.0f * mean_k * s1n + mean_k * mean_k * cntk;
  float std_k = sqrtf(var_num / ms + 1e-6f);
  float max_k = (mxr - mu) / sd;

  float h = mean_k * W1[e] + std_k * W1[EDIM + e] + max_k * W1[2 * EDIM + e] + b1[e];

  float s = h, q = h * h;
#pragma unroll
  for (int off = 32; off > 0; off >>= 1) {
    s += __shfl_down(s, off);
    q += __shfl_down(q, off);
  }
  __shared__ float rs[4], rq[4];
  __shared__ float hmS, hvS;
  if ((e & 63) == 0) { rs[e >> 6] = s; rq[e >> 6] = q; }
  __syncthreads();
  if (e == 0) {
    float ts = rs[0] + rs[1] + rs[2] + rs[3];
    float tq = rq[0] + rq[1] + rq[2] + rq[3];
    float hm = ts / 256.0f;
    hmS = hm;
    hvS = fmaxf(tq / 256.0f - hm * hm, 0.0f);
  }
  __syncthreads();
  float hn = (h - hmS) / sqrtf(hvS + 1e-5f) * gamma[e] + beta[e];
  float hr = fmaxf(hn, 0.0f);

  __shared__ float hs[EDIM];
  hs[e] = hr;
  __syncthreads();

  float acc = b2[e];
#pragma unroll 8
  for (int j = 0; j < EDIM; j++) acc += hs[j] * W2m[j * EDIM + e];
  out[(size_t)bk * EDIM + e] = acc;
}

// ---- launch ---------------------------------------------------------------
extern "C" void kernel_launch(void* const* d_in, const int* in_sizes, int n_in,
                              void* d_out, int out_size, void* d_ws, size_t ws_size,
                              hipStream_t stream) {
  const float* x     = (const float*)d_in[0];
  const float* W1    = (const float*)d_in[1];
  const float* b1    = (const float*)d_in[2];
  const float* gamma = (const float*)d_in[3];
  const float* beta  = (const float*)d_in[4];
  const float* W2m   = (const float*)d_in[5];
  const float* b2    = (const float*)d_in[6];
  float* out = (float*)d_out;

  char* W = (char*)d_ws;
  f16* B2t = (f16*)W;                                  // [64][128][448] = 7,340,032 B
  f16* B1  = (f16*)(W + 7340032);                      // [256][256]  = 131,072 B
  f16* W2h = (f16*)(W + 7340032 + 131072);             // [448][448]  = 401,408 B
  float* stats = (float*)(W + 7340032 + 131072 + 401408);  // 64*34 f32

  prep_kernel<<<dim3(1889), dim3(256), 0, stream>>>(B1, W2h, B2t, stats);
  gemmA_kernel<<<dim3(224), dim3(256), 0, stream>>>(x, B1, B2t);
  gemmB_kernel<<<dim3(BATCH, 7), dim3(256), 0, stream>>>(W2h, B2t, stats);
  mlp_kernel<<<dim3(BATCH * 8), dim3(256), 0, stream>>>(stats, W1, b1, gamma, beta, W2m, b2, out);
}

// Round 8
// 54.845 us; speedup vs baseline: 1.0308x; 1.0308x over previous
//
#include <hip/hip_runtime.h>
#include <math.h>

#define IMG 224
#define NPIX 50176
#define BATCH 64
#define EDIM 256

typedef _Float16 f16;
typedef __attribute__((ext_vector_type(8))) _Float16 f16x8;
typedef __attribute__((ext_vector_type(4))) _Float16 f16x4;
typedef __attribute__((ext_vector_type(4))) float f32x4;
typedef unsigned int u32;

// All twiddles come from a per-block LDS table T[m] = cospif(m/112) = cos(2πm/224):
//   cos(θm)  = T[m]
//   sin(θm)  = T[(m+168)%224]   (cos(θ+3π/2) = sin θ)
//   -sin(θm) = T[(m+56)%224]    (cos(θ+π/2) = -sin θ)
// GEMM geometry: 4 waves (2Mx2N), 16x16x32 f16 MFMA, XOR-swizzled LDS tiles.
// gemmA: A = gray(x) fused (reg-staged), B = B1 computed in-LDS. 64x256 tile.
// gemmB: A = W2 computed in-LDS, B = B2t via GLD16 (3-deep, vmcnt(4)). 64x128 tile.

#define GLD16(gp, lp)                                                          \
  __builtin_amdgcn_global_load_lds(                                            \
      (const __attribute__((address_space(1))) u32*)(gp),                      \
      (__attribute__((address_space(3))) u32*)(lp), 16, 0, 0)

// ---- gemmA: Y = gray(x) * B1^T -> fp16 B2t; zeroes stats ------------------
__global__ __launch_bounds__(256) void gemmA_kernel(const float* __restrict__ x,
                                                    f16* __restrict__ B2t,
                                                    float* __restrict__ stats) {
  __shared__ float T[224];
  __shared__ f16 As[2][64][64];     // 16 KB
  __shared__ f16 Bs[2][256][64];    // 64 KB
  int m0 = blockIdx.x * 64;
  int tid = threadIdx.x;
  int lane = tid & 63, wid = tid >> 6;
  int wr = wid >> 1, wc = wid & 1;

  if (blockIdx.x == 0) {            // replaces prep's stats zeroing
#pragma unroll
    for (int i = 0; i < 9; ++i) {
      int idx = i * 256 + tid;
      if (idx < BATCH * 34) stats[idx] = 0.f;
    }
  }

  // A reg-staging: thread -> (row, 16-col segment)   [R7-verified]
  int arow = tid >> 2;
  int aseg = tid & 3;
  int am = m0 + arow;
  int ab = am / 224, ah = am - ab * 224;
  const float* px = x + (size_t)ab * 3 * NPIX + ah * IMG;
  int s0 = (aseg * 2) ^ (arow & 7);
  int s1 = (aseg * 2 + 1) ^ (arow & 7);

  f32x4 xl[3][4];
  f32x4 acc[2][8];
#pragma unroll
  for (int i = 0; i < 2; ++i)
#pragma unroll
    for (int j = 0; j < 8; ++j) acc[i][j] = (f32x4){0.f, 0.f, 0.f, 0.f};

  auto issueA = [&](int t) {
    int kb = t * 64 + aseg * 16;
    if (kb < 224) {
#pragma unroll
      for (int c = 0; c < 3; ++c)
#pragma unroll
        for (int q = 0; q < 4; ++q)
          xl[c][q] = *(const f32x4*)(px + c * NPIX + kb + q * 4);
    }
  };
  auto writeA = [&](int bufi, int t) {
    int kb = t * 64 + aseg * 16;
    f16x8 h0, h1;
    if (kb < 224) {
#pragma unroll
      for (int j = 0; j < 8; ++j) {
        int q = j >> 2, r = j & 3;
        h0[j] = (f16)((xl[0][q][r] + xl[1][q][r] + xl[2][q][r]) * (1.0f / 3.0f));
      }
#pragma unroll
      for (int j = 0; j < 8; ++j) {
        int q = 2 + (j >> 2), r = j & 3;
        h1[j] = (f16)((xl[0][q][r] + xl[1][q][r] + xl[2][q][r]) * (1.0f / 3.0f));
      }
    } else {
#pragma unroll
      for (int j = 0; j < 8; ++j) { h0[j] = (f16)0.f; h1[j] = (f16)0.f; }
    }
    *(f16x8*)&As[bufi][arow][s0 * 8] = h0;
    *(f16x8*)&As[bufi][arow][s1 * 8] = h1;
  };
  // B1[n][k]: n<113 -> cos(2π nk/224); n>=113 -> -sin(2π (n-113)k/224)
  auto computeB = [&](int bufi, int t) {
    int row = tid;
    int v = (row < 113) ? row : row - 113;
    u32 off = (row < 113) ? 0u : 56u;
    u32 idx = ((u32)(t * 64) * (u32)v + off) % 224u;
#pragma unroll
    for (int g = 0; g < 8; ++g) {
      f16x8 hv;
#pragma unroll
      for (int j = 0; j < 8; ++j) {
        hv[j] = (f16)T[idx];
        idx += v; if (idx >= 224u) idx -= 224u;
      }
      *(f16x8*)&Bs[bufi][row][(g ^ (row & 7)) * 8] = hv;
    }
  };

  issueA(0);
  if (tid < 224) T[tid] = cospif((float)tid / 112.0f);
  __syncthreads();
  computeB(0, 0);

#pragma unroll 1
  for (int t = 0; t < 4; ++t) {
    int cur = t & 1;
    asm volatile("s_waitcnt vmcnt(0)" ::: "memory");   // x regs for tile t landed
    writeA(cur, t);
    asm volatile("s_waitcnt lgkmcnt(0)" ::: "memory");
    __builtin_amdgcn_s_barrier();                      // tile t fully staged
    if (t < 3) { issueA(t + 1); computeB(cur ^ 1, t + 1); }
#pragma unroll
    for (int kk = 0; kk < 2; ++kk) {
      f16x8 af[2], bfr[8];
#pragma unroll
      for (int mi = 0; mi < 2; ++mi) {
        int row = wr * 32 + mi * 16 + (lane & 15);
        int slot = (kk * 4 + (lane >> 4)) ^ (row & 7);
        af[mi] = *(const f16x8*)&As[cur][row][slot * 8];
      }
#pragma unroll
      for (int nj = 0; nj < 8; ++nj) {
        int row = wc * 128 + nj * 16 + (lane & 15);
        int slot = (kk * 4 + (lane >> 4)) ^ (row & 7);
        bfr[nj] = *(const f16x8*)&Bs[cur][row][slot * 8];
      }
#pragma unroll
      for (int mi = 0; mi < 2; ++mi)
#pragma unroll
        for (int nj = 0; nj < 8; ++nj)
          acc[mi][nj] = __builtin_amdgcn_mfma_f32_16x16x32_f16(
              af[mi], bfr[nj], acc[mi][nj], 0, 0, 0);
    }
    __builtin_amdgcn_s_barrier();
  }

  int mbase = m0 + wr * 32, nbase = wc * 128;
#pragma unroll
  for (int mi = 0; mi < 2; ++mi) {
#pragma unroll
    for (int nj = 0; nj < 8; ++nj) {
      int c = nbase + nj * 16 + (lane & 15);
      if (c >= 226) continue;
      int m = mbase + mi * 16 + ((lane >> 4) << 2);  // 4 consecutive rows, m%4==0
      int b = m / 224;
      int h = m - b * 224;                           // h%4==0, no image wrap
      int v = c, kb = h;
      if (c >= 113) { v = c - 113; kb = 224 + h; }
      size_t off = (size_t)(b * 128 + v) * 448 + kb;
      f32x4 y = acc[mi][nj];
      f16x4 hv;
#pragma unroll
      for (int r = 0; r < 4; ++r) hv[r] = (f16)y[r];
      *(f16x4*)&B2t[off] = hv;
    }
  }
}

// ---- gemmB: F = W2 * B2t[b]^T; fused log1p(|F|) + band stats --------------
// stats layout: [0]=gsum [1]=gsumsq [2+k]=s1 [10+k]=s2 [18+k]=max [26+k]=cnt
__global__ __launch_bounds__(256) void gemmB_kernel(const f16* __restrict__ B2t,
                                                    float* __restrict__ stats) {
  __shared__ float T[224];
  __shared__ f16 As[2][64][64];     // 16 KB (VALU-computed W2 tile)
  __shared__ f16 Bs[3][128][64];    // 48 KB (3-deep GLD16 pipeline)
  int tid = threadIdx.x;
  int lane = tid & 63, wid = tid >> 6;
  int wr = wid >> 1, wc = wid & 1;

  // XCD-chunked swizzle: each XCD gets 8 whole images (56 blocks). 448 = 8*56.
  int bid = blockIdx.x;
  int nb = (bid & 7) * 56 + (bid >> 3);
  int b = nb / 7;
  int m0 = (nb - b * 7) * 64;
  const f16* Bb = B2t + (size_t)b * 128 * 448;

  int srow = lane >> 3;
  int sk8 = (lane & 7) ^ srow;

  f32x4 acc[2][4];
#pragma unroll
  for (int i = 0; i < 2; ++i)
#pragma unroll
    for (int j = 0; j < 4; ++j) acc[i][j] = (f32x4){0.f, 0.f, 0.f, 0.f};

  auto issueB = [&](int t) {
    int k0 = t * 64;
    int bi = t % 3;
#pragma unroll
    for (int ci = 0; ci < 4; ++ci) {
      int j = wid * 4 + ci;   // 0..15 chunks of 8 rows
      GLD16(Bb + (size_t)(j * 8 + srow) * 448 + k0 + sk8 * 8,
            &Bs[bi][0][0] + j * 512);
    }
  };
  // W2 row 2u (re): k<224 -> cos, k>=224 -> sin ; row 2u+1 (im): -sin / cos
  auto computeA = [&](int bufi, int t) {
    int row = tid >> 2, seg = tid & 3;
    int rr = m0 + row;
    u32 u = (u32)(rr >> 1);
    int imrow = rr & 1;
    int kb = t * 64 + seg * 16;
    int kim = kb >= 224;
    u32 kq = (u32)(kb - (kim ? 224 : 0));
    u32 off = imrow ? (kim ? 0u : 56u) : (kim ? 168u : 0u);
    u32 idx = (u * kq + off) % 224u;
#pragma unroll
    for (int g = 0; g < 2; ++g) {
      f16x8 hv;
#pragma unroll
      for (int j = 0; j < 8; ++j) {
        hv[j] = (f16)T[idx];
        idx += u; if (idx >= 224u) idx -= 224u;
      }
      int lg = seg * 2 + g;
      *(f16x8*)&As[bufi][row][(lg ^ (row & 7)) * 8] = hv;
    }
  };

  if (tid < 224) T[tid] = cospif((float)tid / 112.0f);
  issueB(0);
  issueB(1);
  __syncthreads();
  computeA(0, 0);

#pragma unroll 1
  for (int t = 0; t < 7; ++t) {
    int cur = t & 1;
    if (t < 6) {
      asm volatile("s_waitcnt vmcnt(4)" ::: "memory");  // tile t landed, t+1 in flight
    } else {
      asm volatile("s_waitcnt vmcnt(0)" ::: "memory");
    }
    asm volatile("s_waitcnt lgkmcnt(0)" ::: "memory");
    __builtin_amdgcn_s_barrier();                       // tile t ready
    if (t + 2 <= 6) issueB(t + 2);
    if (t < 6) computeA(cur ^ 1, t + 1);
    int bcur = t % 3;
#pragma unroll
    for (int kk = 0; kk < 2; ++kk) {
      f16x8 af[2], bfr[4];
#pragma unroll
      for (int mi = 0; mi < 2; ++mi) {
        int row = wr * 32 + mi * 16 + (lane & 15);
        int slot = (kk * 4 + (lane >> 4)) ^ (row & 7);
        af[mi] = *(const f16x8*)&As[cur][row][slot * 8];
      }
#pragma unroll
      for (int nj = 0; nj < 4; ++nj) {
        int row = wc * 64 + nj * 16 + (lane & 15);
        int slot = (kk * 4 + (lane >> 4)) ^ (row & 7);
        bfr[nj] = *(const f16x8*)&Bs[bcur][row][slot * 8];
      }
#pragma unroll
      for (int mi = 0; mi < 2; ++mi)
#pragma unroll
        for (int nj = 0; nj < 4; ++nj)
          acc[mi][nj] = __builtin_amdgcn_mfma_f32_16x16x32_f16(
              af[mi], bfr[nj], acc[mi][nj], 0, 0, 0);
    }
    __builtin_amdgcn_s_barrier();
  }

  // fused stats epilogue (verified R6/R7)
  int rbase = m0 + wr * 32;
  const float step = (float)(158.39191898578665 / 8.0);
  float gsum = 0.f, gsq = 0.f;
  float s1[8] = {0}, s2[8] = {0}, cnt[8] = {0};
  float mx[8] = {0, 0, 0, 0, 0, 0, 0, 0};   // mag >= 0 always

#pragma unroll
  for (int mi = 0; mi < 2; ++mi) {
#pragma unroll
    for (int nj = 0; nj < 4; ++nj) {
      int n = wc * 64 + nj * 16 + (lane & 15);   // v, 0..127
      if (n >= 113) continue;
      float wgt = (n >= 1 && n <= 111) ? 2.f : 1.f;   // Hermitian mirror weight
      float dx2 = (float)(n * n);
      int rr = rbase + mi * 16 + ((lane >> 4) << 2);
      f32x4 f = acc[mi][nj];
#pragma unroll
      for (int p = 0; p < 2; ++p) {
        int u = (rr >> 1) + p;
        float re = f[2 * p], im = f[2 * p + 1];
        float mv = log1pf(sqrtf(re * re + im * im));
        int a = (u <= 111) ? u : 224 - u;
        float r = sqrtf((float)(a * a) + dx2);
        int bd = 255;
#pragma unroll
        for (int k = 0; k < 8; k++) {
          float lo = step * (float)k;
          float hi = step * (float)(k + 1);
          if (r >= lo && r < hi) bd = k;
        }
        float wm = wgt * mv;
        gsum += wm;
        gsq += wm * mv;
#pragma unroll
        for (int k = 0; k < 8; k++) {
          bool m = (bd == k);
          s1[k] += m ? wm : 0.f;
          s2[k] += m ? wm * mv : 0.f;
          cnt[k] += m ? wgt : 0.f;
          mx[k] = m ? fmaxf(mx[k], mv) : mx[k];
        }
      }
    }
  }

  float vals[34];
  vals[0] = gsum; vals[1] = gsq;
#pragma unroll
  for (int k = 0; k < 8; k++) {
    vals[2 + k] = s1[k]; vals[10 + k] = s2[k]; vals[18 + k] = mx[k]; vals[26 + k] = cnt[k];
  }
#pragma unroll
  for (int i = 0; i < 34; i++) {
    float v = vals[i];
    const bool isMax = (i >= 18 && i < 26);
#pragma unroll
    for (int off = 32; off > 0; off >>= 1) {
      float o = __shfl_down(v, off);
      v = isMax ? fmaxf(v, o) : (v + o);
    }
    vals[i] = v;
  }
  float* red = (float*)&As[0][0][0];   // reuse LDS (all reads done)
  if ((tid & 63) == 0) {
#pragma unroll
    for (int i = 0; i < 34; i++) red[wid * 34 + i] = vals[i];
  }
  __syncthreads();
  if (tid < 34) {
    bool isMax = (tid >= 18 && tid < 26);
    float v = red[tid];
#pragma unroll
    for (int ww = 1; ww < 4; ww++) {
      float o = red[ww * 34 + tid];
      v = isMax ? fmaxf(v, o) : (v + o);
    }
    if (isMax)
      atomicMax((u32*)&stats[b * 34 + tid], __float_as_uint(v));  // v >= 0
    else
      atomicAdd(&stats[b * 34 + tid], v);
  }
}

// ---- MLP ------------------------------------------------------------------
__global__ __launch_bounds__(256) void mlp_kernel(const float* __restrict__ stats,
                                                  const float* __restrict__ W1,
                                                  const float* __restrict__ b1,
                                                  const float* __restrict__ gamma,
                                                  const float* __restrict__ beta,
                                                  const float* __restrict__ W2m,
                                                  const float* __restrict__ b2,
                                                  float* __restrict__ out) {
  int bk = blockIdx.x;
  int b = bk >> 3, k = bk & 7;
  int e = threadIdx.x;

  __shared__ float st[34];
  if (e < 34) st[e] = stats[b * 34 + e];
  __syncthreads();

  const float N = (float)NPIX;
  float mu = st[0] / N;
  float varg = fmaxf(st[1] - N * mu * mu, 0.0f) / (N - 1.0f);
  float sd = sqrtf(varg) + 1e-6f;

  float s1r = st[2 + k], s2r = st[10 + k], mxr = st[18 + k], cntk = st[26 + k];
  float ms = cntk + 1e-6f;
  float s1n = (s1r - mu * cntk) / sd;
  float s2n = (s2r - 2.0f * mu * s1r + mu * mu * cntk) / (sd * sd);
  float mean_k = s1n / ms;
  float var_num = s2n - 2.0f * mean_k * s1n + mean_k * mean_k * cntk;
  float std_k = sqrtf(var_num / ms + 1e-6f);
  float max_k = (mxr - mu) / sd;

  float h = mean_k * W1[e] + std_k * W1[EDIM + e] + max_k * W1[2 * EDIM + e] + b1[e];

  float s = h, q = h * h;
#pragma unroll
  for (int off = 32; off > 0; off >>= 1) {
    s += __shfl_down(s, off);
    q += __shfl_down(q, off);
  }
  __shared__ float rs[4], rq[4];
  __shared__ float hmS, hvS;
  if ((e & 63) == 0) { rs[e >> 6] = s; rq[e >> 6] = q; }
  __syncthreads();
  if (e == 0) {
    float ts = rs[0] + rs[1] + rs[2] + rs[3];
    float tq = rq[0] + rq[1] + rq[2] + rq[3];
    float hm = ts / 256.0f;
    hmS = hm;
    hvS = fmaxf(tq / 256.0f - hm * hm, 0.0f);
  }
  __syncthreads();
  float hn = (h - hmS) / sqrtf(hvS + 1e-5f) * gamma[e] + beta[e];
  float hr = fmaxf(hn, 0.0f);

  __shared__ float hs[EDIM];
  hs[e] = hr;
  __syncthreads();

  float acc = b2[e];
#pragma unroll 8
  for (int j = 0; j < EDIM; j++) acc += hs[j] * W2m[j * EDIM + e];
  out[(size_t)bk * EDIM + e] = acc;
}

// ---- launch ---------------------------------------------------------------
extern "C" void kernel_launch(void* const* d_in, const int* in_sizes, int n_in,
                              void* d_out, int out_size, void* d_ws, size_t ws_size,
                              hipStream_t stream) {
  const float* x     = (const float*)d_in[0];
  const float* W1    = (const float*)d_in[1];
  const float* b1    = (const float*)d_in[2];
  const float* gamma = (const float*)d_in[3];
  const float* beta  = (const float*)d_in[4];
  const float* W2m   = (const float*)d_in[5];
  const float* b2    = (const float*)d_in[6];
  float* out = (float*)d_out;

  char* W = (char*)d_ws;
  f16* B2t = (f16*)W;                       // [64][128][448] = 7,340,032 B
  float* stats = (float*)(W + 7340032);     // 64*34 f32

  gemmA_kernel<<<dim3(224), dim3(256), 0, stream>>>(x, B2t, stats);
  gemmB_kernel<<<dim3(448), dim3(256), 0, stream>>>(B2t, stats);
  mlp_kernel<<<dim3(BATCH * 8), dim3(256), 0, stream>>>(stats, W1, b1, gamma, beta, W2m, b2, out);
}

// Round 9
// 49.887 us; speedup vs baseline: 1.1333x; 1.0994x over previous
//
#include <hip/hip_runtime.h>
#include <math.h>

#define IMG 224
#define NPIX 50176
#define BATCH 64
#define EDIM 256

typedef _Float16 f16;
typedef __attribute__((ext_vector_type(8))) _Float16 f16x8;
typedef __attribute__((ext_vector_type(4))) _Float16 f16x4;
typedef __attribute__((ext_vector_type(4))) float f32x4;
typedef unsigned int u32;

// Twiddles: T[m] = cos(2πm/224); sin = T[(m+168)%224]; -sin = T[(m+56)%224].
// Per-thread runs walk a fixed angle step φ, so elements come from the
// Chebyshev recurrence c_{k+1} = 2cosφ·c_k − c_{k−1} (seeded by 2 T-lookups).
// gemmA: 32x256 tile, 448 blocks (74.6 KB LDS -> 2 blocks/CU), A=gray(x)
//   reg-staged, B=B1 recurrence-computed in LDS.
// gemmB: 64x128 tile, 448 blocks, A=W2 recurrence-computed, B=B2t via GLD16
//   (3-deep, vmcnt(4)); epilogue log1p(|F|) + radial band stats (atomics).

#define GLD16(gp, lp)                                                          \
  __builtin_amdgcn_global_load_lds(                                            \
      (const __attribute__((address_space(1))) u32*)(gp),                      \
      (__attribute__((address_space(3))) u32*)(lp), 16, 0, 0)

// ---- gemmA: Y = gray(x) * B1^T -> fp16 B2t; zeroes stats ------------------
__global__ __launch_bounds__(256) void gemmA_kernel(const float* __restrict__ x,
                                                    f16* __restrict__ B2t,
                                                    float* __restrict__ stats) {
  __shared__ float T[224];
  __shared__ f16 As[2][32][64];     // 8 KB
  __shared__ f16 Bs[2][256][64];    // 64 KB
  int m0 = blockIdx.x * 32;
  int tid = threadIdx.x;
  int lane = tid & 63, wid = tid >> 6;

  if (blockIdx.x == 0) {            // stats zeroing (stream-ordered before gemmB)
#pragma unroll
    for (int i = 0; i < 9; ++i) {
      int idx = i * 256 + tid;
      if (idx < BATCH * 34) stats[idx] = 0.f;
    }
  }

  // A reg-staging: thread -> (row 0..31, 8-col segment 0..7)
  int arow = tid >> 3;
  int aseg = tid & 7;
  int am = m0 + arow;
  int ab = am / 224, ah = am - ab * 224;
  const float* px = x + (size_t)ab * 3 * NPIX + ah * IMG;
  int s0 = aseg ^ (arow & 7);       // swizzled 16B slot (involution)

  f32x4 xl[3][2];
  f32x4 acc[2][4];
#pragma unroll
  for (int i = 0; i < 2; ++i)
#pragma unroll
    for (int j = 0; j < 4; ++j) acc[i][j] = (f32x4){0.f, 0.f, 0.f, 0.f};

  auto issueA = [&](int t) {
    int kb = t * 64 + aseg * 8;
    if (kb < 224) {
#pragma unroll
      for (int c = 0; c < 3; ++c) {
        xl[c][0] = *(const f32x4*)(px + c * NPIX + kb);
        xl[c][1] = *(const f32x4*)(px + c * NPIX + kb + 4);
      }
    }
  };
  auto writeA = [&](int bufi, int t) {
    int kb = t * 64 + aseg * 8;
    f16x8 h0;
    if (kb < 224) {
#pragma unroll
      for (int j = 0; j < 8; ++j) {
        int q = j >> 2, r = j & 3;
        h0[j] = (f16)((xl[0][q][r] + xl[1][q][r] + xl[2][q][r]) * (1.0f / 3.0f));
      }
    } else {
#pragma unroll
      for (int j = 0; j < 8; ++j) h0[j] = (f16)0.f;
    }
    *(f16x8*)&As[bufi][arow][s0 * 8] = h0;
  };
  // B1[n][k]: n<113 -> cos(2π nk/224); n>=113 -> -sin(2π (n-113)k/224)
  auto computeB = [&](int bufi, int t) {
    int row = tid;
    int v = (row < 113) ? row : row - 113;
    u32 off = (row < 113) ? 0u : 56u;
    u32 idx0 = ((u32)(t * 64) * (u32)v + off) % 224u;
    u32 idxm = (idx0 >= (u32)v) ? idx0 - (u32)v : idx0 + 224u - (u32)v;
    float cur = T[idx0];
    float prev = T[idxm];
    float k2c = 2.0f * T[v];
#pragma unroll
    for (int g = 0; g < 8; ++g) {
      f16x8 hv;
#pragma unroll
      for (int j = 0; j < 8; ++j) {
        hv[j] = (f16)cur;
        float nxt = __builtin_fmaf(k2c, cur, -prev);
        prev = cur; cur = nxt;
      }
      *(f16x8*)&Bs[bufi][row][(g ^ (row & 7)) * 8] = hv;
    }
  };

  issueA(0);
  if (tid < 224) T[tid] = cospif((float)tid / 112.0f);
  __syncthreads();
  computeB(0, 0);

#pragma unroll 1
  for (int t = 0; t < 4; ++t) {
    int cur = t & 1;
    asm volatile("s_waitcnt vmcnt(0)" ::: "memory");   // x regs for tile t landed
    writeA(cur, t);
    asm volatile("s_waitcnt lgkmcnt(0)" ::: "memory");
    __builtin_amdgcn_s_barrier();                      // tile t fully staged
    if (t < 3) { issueA(t + 1); computeB(cur ^ 1, t + 1); }
#pragma unroll
    for (int kk = 0; kk < 2; ++kk) {
      f16x8 af[2], bfr[4];
#pragma unroll
      for (int mi = 0; mi < 2; ++mi) {
        int row = mi * 16 + (lane & 15);
        int slot = (kk * 4 + (lane >> 4)) ^ (row & 7);
        af[mi] = *(const f16x8*)&As[cur][row][slot * 8];
      }
#pragma unroll
      for (int nj = 0; nj < 4; ++nj) {
        int row = wid * 64 + nj * 16 + (lane & 15);
        int slot = (kk * 4 + (lane >> 4)) ^ (row & 7);
        bfr[nj] = *(const f16x8*)&Bs[cur][row][slot * 8];
      }
#pragma unroll
      for (int mi = 0; mi < 2; ++mi)
#pragma unroll
        for (int nj = 0; nj < 4; ++nj)
          acc[mi][nj] = __builtin_amdgcn_mfma_f32_16x16x32_f16(
              af[mi], bfr[nj], acc[mi][nj], 0, 0, 0);
    }
    __builtin_amdgcn_s_barrier();
  }

  int nbase = wid * 64;
#pragma unroll
  for (int mi = 0; mi < 2; ++mi) {
#pragma unroll
    for (int nj = 0; nj < 4; ++nj) {
      int c = nbase + nj * 16 + (lane & 15);
      if (c >= 226) continue;
      int m = m0 + mi * 16 + ((lane >> 4) << 2);     // 4 consecutive rows, m%4==0
      int b = m / 224;
      int h = m - b * 224;                           // block never straddles images
      int v = c, kb = h;
      if (c >= 113) { v = c - 113; kb = 224 + h; }
      size_t off = (size_t)(b * 128 + v) * 448 + kb;
      f32x4 y = acc[mi][nj];
      f16x4 hv;
#pragma unroll
      for (int r = 0; r < 4; ++r) hv[r] = (f16)y[r];
      *(f16x4*)&B2t[off] = hv;
    }
  }
}

// ---- gemmB: F = W2 * B2t[b]^T; fused log1p(|F|) + band stats --------------
// stats layout: [0]=gsum [1]=gsumsq [2+k]=s1 [10+k]=s2 [18+k]=max [26+k]=cnt
__global__ __launch_bounds__(256) void gemmB_kernel(const f16* __restrict__ B2t,
                                                    float* __restrict__ stats) {
  __shared__ float T[224];
  __shared__ f16 As[2][64][64];     // 16 KB (recurrence-computed W2 tile)
  __shared__ f16 Bs[3][128][64];    // 48 KB (3-deep GLD16 pipeline)
  int tid = threadIdx.x;
  int lane = tid & 63, wid = tid >> 6;
  int wr = wid >> 1, wc = wid & 1;

  // XCD-chunked swizzle: each XCD gets 8 whole images (56 blocks). 448 = 8*56.
  int bid = blockIdx.x;
  int nb = (bid & 7) * 56 + (bid >> 3);
  int b = nb / 7;
  int m0 = (nb - b * 7) * 64;
  const f16* Bb = B2t + (size_t)b * 128 * 448;

  int srow = lane >> 3;
  int sk8 = (lane & 7) ^ srow;

  f32x4 acc[2][4];
#pragma unroll
  for (int i = 0; i < 2; ++i)
#pragma unroll
    for (int j = 0; j < 4; ++j) acc[i][j] = (f32x4){0.f, 0.f, 0.f, 0.f};

  auto issueB = [&](int t) {
    int k0 = t * 64;
    int bi = t % 3;
#pragma unroll
    for (int ci = 0; ci < 4; ++ci) {
      int j = wid * 4 + ci;   // 0..15 chunks of 8 rows
      GLD16(Bb + (size_t)(j * 8 + srow) * 448 + k0 + sk8 * 8,
            &Bs[bi][0][0] + j * 512);
    }
  };
  // W2 row 2u (re): k<224 -> cos, k>=224 -> sin ; row 2u+1 (im): -sin / cos
  auto computeA = [&](int bufi, int t) {
    int row = tid >> 2, seg = tid & 3;
    int rr = m0 + row;
    u32 u = (u32)(rr >> 1);
    int imrow = rr & 1;
    int kb = t * 64 + seg * 16;
    int kim = kb >= 224;
    u32 kq = (u32)(kb - (kim ? 224 : 0));
    u32 off = imrow ? (kim ? 0u : 56u) : (kim ? 168u : 0u);
    u32 idx0 = (u * kq + off) % 224u;
    u32 idxm = (idx0 >= u) ? idx0 - u : idx0 + 224u - u;
    float cur = T[idx0];
    float prev = T[idxm];
    float k2c = 2.0f * T[u];
#pragma unroll
    for (int g = 0; g < 2; ++g) {
      f16x8 hv;
#pragma unroll
      for (int j = 0; j < 8; ++j) {
        hv[j] = (f16)cur;
        float nxt = __builtin_fmaf(k2c, cur, -prev);
        prev = cur; cur = nxt;
      }
      *(f16x8*)&As[bufi][row][((seg * 2 + g) ^ (row & 7)) * 8] = hv;
    }
  };

  if (tid < 224) T[tid] = cospif((float)tid / 112.0f);
  issueB(0);
  issueB(1);
  __syncthreads();
  computeA(0, 0);

#pragma unroll 1
  for (int t = 0; t < 7; ++t) {
    int cur = t & 1;
    if (t < 6) {
      asm volatile("s_waitcnt vmcnt(4)" ::: "memory");  // tile t landed, t+1 in flight
    } else {
      asm volatile("s_waitcnt vmcnt(0)" ::: "memory");
    }
    asm volatile("s_waitcnt lgkmcnt(0)" ::: "memory");
    __builtin_amdgcn_s_barrier();                       // tile t ready
    if (t + 2 <= 6) issueB(t + 2);
    if (t < 6) computeA(cur ^ 1, t + 1);
    int bcur = t % 3;
#pragma unroll
    for (int kk = 0; kk < 2; ++kk) {
      f16x8 af[2], bfr[4];
#pragma unroll
      for (int mi = 0; mi < 2; ++mi) {
        int row = wr * 32 + mi * 16 + (lane & 15);
        int slot = (kk * 4 + (lane >> 4)) ^ (row & 7);
        af[mi] = *(const f16x8*)&As[cur][row][slot * 8];
      }
#pragma unroll
      for (int nj = 0; nj < 4; ++nj) {
        int row = wc * 64 + nj * 16 + (lane & 15);
        int slot = (kk * 4 + (lane >> 4)) ^ (row & 7);
        bfr[nj] = *(const f16x8*)&Bs[bcur][row][slot * 8];
      }
#pragma unroll
      for (int mi = 0; mi < 2; ++mi)
#pragma unroll
        for (int nj = 0; nj < 4; ++nj)
          acc[mi][nj] = __builtin_amdgcn_mfma_f32_16x16x32_f16(
              af[mi], bfr[nj], acc[mi][nj], 0, 0, 0);
    }
    __builtin_amdgcn_s_barrier();
  }

  // fused stats epilogue (verified R6-R8)
  int rbase = m0 + wr * 32;
  const float step = (float)(158.39191898578665 / 8.0);
  float gsum = 0.f, gsq = 0.f;
  float s1[8] = {0}, s2[8] = {0}, cnt[8] = {0};
  float mx[8] = {0, 0, 0, 0, 0, 0, 0, 0};   // mag >= 0 always

#pragma unroll
  for (int mi = 0; mi < 2; ++mi) {
#pragma unroll
    for (int nj = 0; nj < 4; ++nj) {
      int n = wc * 64 + nj * 16 + (lane & 15);   // v, 0..127
      if (n >= 113) continue;
      float wgt = (n >= 1 && n <= 111) ? 2.f : 1.f;   // Hermitian mirror weight
      float dx2 = (float)(n * n);
      int rr = rbase + mi * 16 + ((lane >> 4) << 2);
      f32x4 f = acc[mi][nj];
#pragma unroll
      for (int p = 0; p < 2; ++p) {
        int u = (rr >> 1) + p;
        float re = f[2 * p], im = f[2 * p + 1];
        float mv = log1pf(sqrtf(re * re + im * im));
        int a = (u <= 111) ? u : 224 - u;
        float r = sqrtf((float)(a * a) + dx2);
        int bd = 255;
#pragma unroll
        for (int k = 0; k < 8; k++) {
          float lo = step * (float)k;
          float hi = step * (float)(k + 1);
          if (r >= lo && r < hi) bd = k;
        }
        float wm = wgt * mv;
        gsum += wm;
        gsq += wm * mv;
#pragma unroll
        for (int k = 0; k < 8; k++) {
          bool m = (bd == k);
          s1[k] += m ? wm : 0.f;
          s2[k] += m ? wm * mv : 0.f;
          cnt[k] += m ? wgt : 0.f;
          mx[k] = m ? fmaxf(mx[k], mv) : mx[k];
        }
      }
    }
  }

  float vals[34];
  vals[0] = gsum; vals[1] = gsq;
#pragma unroll
  for (int k = 0; k < 8; k++) {
    vals[2 + k] = s1[k]; vals[10 + k] = s2[k]; vals[18 + k] = mx[k]; vals[26 + k] = cnt[k];
  }
#pragma unroll
  for (int i = 0; i < 34; i++) {
    float v = vals[i];
    const bool isMax = (i >= 18 && i < 26);
#pragma unroll
    for (int off = 32; off > 0; off >>= 1) {
      float o = __shfl_down(v, off);
      v = isMax ? fmaxf(v, o) : (v + o);
    }
    vals[i] = v;
  }
  float* red = (float*)&As[0][0][0];   // reuse LDS (all reads done)
  if ((tid & 63) == 0) {
#pragma unroll
    for (int i = 0; i < 34; i++) red[wid * 34 + i] = vals[i];
  }
  __syncthreads();
  if (tid < 34) {
    bool isMax = (tid >= 18 && tid < 26);
    float v = red[tid];
#pragma unroll
    for (int ww = 1; ww < 4; ww++) {
      float o = red[ww * 34 + tid];
      v = isMax ? fmaxf(v, o) : (v + o);
    }
    if (isMax)
      atomicMax((u32*)&stats[b * 34 + tid], __float_as_uint(v));  // v >= 0
    else
      atomicAdd(&stats[b * 34 + tid], v);
  }
}

// ---- MLP: 256 blocks, 2 bands each, shared-j W2m loop ---------------------
__global__ __launch_bounds__(256) void mlp_kernel(const float* __restrict__ stats,
                                                  const float* __restrict__ W1,
                                                  const float* __restrict__ b1,
                                                  const float* __restrict__ gamma,
                                                  const float* __restrict__ beta,
                                                  const float* __restrict__ W2m,
                                                  const float* __restrict__ b2,
                                                  float* __restrict__ out) {
  int blk = blockIdx.x;
  int b = blk >> 2;
  int k0 = (blk & 3) * 2;
  int e = threadIdx.x;
  int lane = e & 63, wave = e >> 6;

  __shared__ float st[34];
  if (e < 34) st[e] = stats[b * 34 + e];
  __syncthreads();

  const float N = (float)NPIX;
  float mu = st[0] / N;
  float varg = fmaxf(st[1] - N * mu * mu, 0.0f) / (N - 1.0f);
  float sd = sqrtf(varg) + 1e-6f;

  float g_e = gamma[e], bt_e = beta[e], b1_e = b1[e];
  float w1a = W1[e], w1b = W1[EDIM + e], w1c = W1[2 * EDIM + e];

  float h[2];
#pragma unroll
  for (int q = 0; q < 2; ++q) {
    int k = k0 + q;
    float s1r = st[2 + k], s2r = st[10 + k], mxr = st[18 + k], cntk = st[26 + k];
    float ms = cntk + 1e-6f;
    float s1n = (s1r - mu * cntk) / sd;
    float s2n = (s2r - 2.0f * mu * s1r + mu * mu * cntk) / (sd * sd);
    float mean_k = s1n / ms;
    float var_num = s2n - 2.0f * mean_k * s1n + mean_k * mean_k * cntk;
    float std_k = sqrtf(var_num / ms + 1e-6f);
    float max_k = (mxr - mu) / sd;
    h[q] = mean_k * w1a + std_k * w1b + max_k * w1c + b1_e;
  }

  // joint LayerNorm reductions for both bands
  float v4[4] = {h[0], h[0] * h[0], h[1], h[1] * h[1]};
#pragma unroll
  for (int i = 0; i < 4; ++i) {
#pragma unroll
    for (int off = 32; off > 0; off >>= 1) v4[i] += __shfl_down(v4[i], off);
  }
  __shared__ float red[4][4];
  __shared__ float mm[4];            // hm0, hv0, hm1, hv1
  if (lane == 0) {
#pragma unroll
    for (int i = 0; i < 4; ++i) red[wave][i] = v4[i];
  }
  __syncthreads();
  if (e == 0) {
#pragma unroll
    for (int i = 0; i < 4; ++i) {
      float t = red[0][i] + red[1][i] + red[2][i] + red[3][i];
      red[0][i] = t;
    }
    float hm0 = red[0][0] / 256.0f, hm1 = red[0][2] / 256.0f;
    mm[0] = hm0;
    mm[1] = fmaxf(red[0][1] / 256.0f - hm0 * hm0, 0.0f);
    mm[2] = hm1;
    mm[3] = fmaxf(red[0][3] / 256.0f - hm1 * hm1, 0.0f);
  }
  __syncthreads();

  __shared__ float hsT[EDIM][2];
#pragma unroll
  for (int q = 0; q < 2; ++q) {
    float hn = (h[q] - mm[2 * q]) / sqrtf(mm[2 * q + 1] + 1e-5f) * g_e + bt_e;
    hsT[e][q] = fmaxf(hn, 0.0f);
  }
  __syncthreads();

  float a0 = b2[e], a1 = a0;
#pragma unroll 8
  for (int j = 0; j < EDIM; j++) {
    float w = W2m[j * EDIM + e];
    float2 hp = *(const float2*)&hsT[j][0];
    a0 += hp.x * w;
    a1 += hp.y * w;
  }
  out[(size_t)(b * 8 + k0) * EDIM + e] = a0;
  out[(size_t)(b * 8 + k0 + 1) * EDIM + e] = a1;
}

// ---- launch ---------------------------------------------------------------
extern "C" void kernel_launch(void* const* d_in, const int* in_sizes, int n_in,
                              void* d_out, int out_size, void* d_ws, size_t ws_size,
                              hipStream_t stream) {
  const float* x     = (const float*)d_in[0];
  const float* W1    = (const float*)d_in[1];
  const float* b1    = (const float*)d_in[2];
  const float* gamma = (const float*)d_in[3];
  const float* beta  = (const float*)d_in[4];
  const float* W2m   = (const float*)d_in[5];
  const float* b2    = (const float*)d_in[6];
  float* out = (float*)d_out;

  char* W = (char*)d_ws;
  f16* B2t = (f16*)W;                       // [64][128][448] = 7,340,032 B
  float* stats = (float*)(W + 7340032);     // 64*34 f32

  gemmA_kernel<<<dim3(448), dim3(256), 0, stream>>>(x, B2t, stats);
  gemmB_kernel<<<dim3(448), dim3(256), 0, stream>>>(B2t, stats);
  mlp_kernel<<<dim3(256), dim3(256), 0, stream>>>(stats, W1, b1, gamma, beta, W2m, b2, out);
}